// Round 3
// baseline (1632.604 us; speedup 1.0000x reference)
//
#include <hip/hip_runtime.h>
#include <math.h>

// Problem constants
#define F_DIM 321
#define H_DIM 4200
#define T_DIM 1000
#define NBC   16      // B*C = 8*2
#define KTOP  3
#define PADV  1e-8f
#define NSPLIT 4      // H-direction split across blocks

// GEMM tiling
#define BM 128        // h rows per block tile
#define BN 128        // t cols per block tile
#define BK 64
#define LDK 132       // padded LDS row stride (words), 16B-aligned rows
#define NHT 33        // ceil(H_DIM / BM)

__device__ __forceinline__ void ins3(float v, int i,
                                     float& v0, float& v1, float& v2,
                                     int& i0, int& i1, int& i2) {
  // strict '>' keeps earlier (smaller-h) entries ahead on ties == lax.top_k
  if (v > v0)      { v2 = v1; i2 = i1; v1 = v0; i1 = i0; v0 = v; i0 = i; }
  else if (v > v1) { v2 = v1; i2 = i1; v1 = v;  i1 = i; }
  else if (v > v2) { v2 = v;  i2 = i; }
}

// K1: fused fp32 GEMM (nominee = integral_m @ mag[bc]) + running top-3 over h.
// Each block: one (t-tile, bc, h-split). Writes partial top-3 (val,idx) to ws.
__global__ __launch_bounds__(256, 2)
void hi_k1_gemm_top3(const float* __restrict__ mag,
                     const float* __restrict__ im,
                     float* __restrict__ wv, int* __restrict__ wi) {
  const int tid = threadIdx.x;
  const int tx = tid & 15;        // 16 col-groups of 8
  const int ty = tid >> 4;        // 16 row-groups of 8
  const int t0 = blockIdx.x * BN;
  const int bc = blockIdx.y;
  const int sp = blockIdx.z;
  const int ht_begin = (sp * NHT) / NSPLIT;
  const int ht_end   = ((sp + 1) * NHT) / NSPLIT;

  __shared__ __align__(16) float As[BK * LDK];  // A^T tile: As[k][h]
  __shared__ __align__(16) float Bs[BK * LDK];  // B tile:   Bs[k][t]
  // merge scratch aliases As (used only between barriers after compute)
  float* mv = As;                                   // [4 waves][BN][3]
  int*   mi = (int*)(As + 4 * BN * KTOP);

  const float* magbc = mag + (size_t)bc * F_DIM * T_DIM;

  float gv0 = -INFINITY, gv1 = -INFINITY, gv2 = -INFINITY;
  int   gi0 = 0, gi1 = 0, gi2 = 0;

  for (int ht = ht_begin; ht < ht_end; ++ht) {
    const int h0 = ht * BM;
    float acc[8][8];
#pragma unroll
    for (int r = 0; r < 8; ++r)
#pragma unroll
      for (int c = 0; c < 8; ++c) acc[r][c] = 0.f;

    // 5 full K-tiles of 64 cover k=0..319 (F=321 -> tail k=320 handled after)
    for (int kt = 0; kt < 5; ++kt) {
      const int k0 = kt * BK;
      __syncthreads();   // protect As/Bs (incl. mv/mi alias) from prior phase
      // stage A transposed: lanes run over k -> coalesced global rows
#pragma unroll 8
      for (int l = 0; l < 32; ++l) {
        int e = tid + 256 * l;
        int kk = e & 63, hh = e >> 6;
        int gh = h0 + hh;
        As[kk * LDK + hh] = (gh < H_DIM) ? im[(size_t)gh * F_DIM + k0 + kk] : 0.f;
      }
      // stage B: lanes run over t -> coalesced, conflict-free LDS writes
#pragma unroll 8
      for (int l = 0; l < 32; ++l) {
        int e = tid + 256 * l;
        int tl = e & 127, kk = e >> 7;
        int gt = t0 + tl;
        Bs[kk * LDK + tl] = (gt < T_DIM) ? magbc[(size_t)(k0 + kk) * T_DIM + gt] : 0.f;
      }
      __syncthreads();
#pragma unroll 8
      for (int k = 0; k < BK; ++k) {
        const float4 a0 = *reinterpret_cast<const float4*>(&As[k * LDK + ty * 8]);
        const float4 a1 = *reinterpret_cast<const float4*>(&As[k * LDK + ty * 8 + 4]);
        const float4 b0 = *reinterpret_cast<const float4*>(&Bs[k * LDK + tx * 8]);
        const float4 b1 = *reinterpret_cast<const float4*>(&Bs[k * LDK + tx * 8 + 4]);
        float av[8] = {a0.x, a0.y, a0.z, a0.w, a1.x, a1.y, a1.z, a1.w};
        float bv[8] = {b0.x, b0.y, b0.z, b0.w, b1.x, b1.y, b1.z, b1.w};
#pragma unroll
        for (int r = 0; r < 8; ++r)
#pragma unroll
          for (int c = 0; c < 8; ++c)
            acc[r][c] = fmaf(av[r], bv[c], acc[r][c]);
      }
    }
    // K tail: k = 320 (single column), straight from global (L2-resident)
    {
      float av[8], bv[8];
#pragma unroll
      for (int r = 0; r < 8; ++r) {
        int gh = h0 + ty * 8 + r;
        av[r] = (gh < H_DIM) ? im[(size_t)gh * F_DIM + (F_DIM - 1)] : 0.f;
      }
#pragma unroll
      for (int c = 0; c < 8; ++c) {
        int gt = t0 + tx * 8 + c;
        bv[c] = (gt < T_DIM) ? magbc[(size_t)(F_DIM - 1) * T_DIM + gt] : 0.f;
      }
#pragma unroll
      for (int r = 0; r < 8; ++r)
#pragma unroll
        for (int c = 0; c < 8; ++c)
          acc[r][c] = fmaf(av[r], bv[c], acc[r][c]);
    }

    // Phase A: per-thread local top-3 per column over its 8 rows (h ascending)
    float lv[8][3]; int li[8][3];
#pragma unroll
    for (int c = 0; c < 8; ++c) {
      lv[c][0] = lv[c][1] = lv[c][2] = -INFINITY;
      li[c][0] = li[c][1] = li[c][2] = 0;
#pragma unroll
      for (int r = 0; r < 8; ++r) {
        int gh = h0 + ty * 8 + r;
        float v = (gh < H_DIM) ? acc[r][c] : -INFINITY;
        ins3(v, gh, lv[c][0], lv[c][1], lv[c][2], li[c][0], li[c][1], li[c][2]);
      }
    }
    // Phase B: merge across the 4 ty values inside each wave (h ascending)
#pragma unroll
    for (int s = 0; s < 2; ++s) {
      const int off = 16 << s;
#pragma unroll
      for (int c = 0; c < 8; ++c) {
        float ov0 = __shfl_down(lv[c][0], off);
        float ov1 = __shfl_down(lv[c][1], off);
        float ov2 = __shfl_down(lv[c][2], off);
        int   oi0 = __shfl_down(li[c][0], off);
        int   oi1 = __shfl_down(li[c][1], off);
        int   oi2 = __shfl_down(li[c][2], off);
        ins3(ov0, oi0, lv[c][0], lv[c][1], lv[c][2], li[c][0], li[c][1], li[c][2]);
        ins3(ov1, oi1, lv[c][0], lv[c][1], lv[c][2], li[c][0], li[c][1], li[c][2]);
        ins3(ov2, oi2, lv[c][0], lv[c][1], lv[c][2], li[c][0], li[c][1], li[c][2]);
      }
    }
    __syncthreads();   // everyone done reading As before aliasing it
    if ((ty & 3) == 0) {
      const int w = ty >> 2;   // wave index 0..3
#pragma unroll
      for (int c = 0; c < 8; ++c) {
        int col = tx * 8 + c;
#pragma unroll
        for (int j = 0; j < 3; ++j) {
          mv[(w * BN + col) * 3 + j] = lv[c][j];
          mi[(w * BN + col) * 3 + j] = li[c][j];
        }
      }
    }
    __syncthreads();
    // Phase C: threads 0..127 own one column; merge 4 wave-lists (h ascending)
    if (tid < BN) {
#pragma unroll
      for (int w = 0; w < 4; ++w)
#pragma unroll
        for (int j = 0; j < 3; ++j) {
          float v = mv[(w * BN + tid) * 3 + j];
          int   i = mi[(w * BN + tid) * 3 + j];
          ins3(v, i, gv0, gv1, gv2, gi0, gi1, gi2);
        }
    }
  }

  if (tid < BN) {
    int t = t0 + tid;
    if (t < T_DIM) {
      size_t base = ((size_t)(bc * NSPLIT + sp) * KTOP) * T_DIM + t;
      wv[base]             = gv0;
      wv[base + T_DIM]     = gv1;
      wv[base + 2 * T_DIM] = gv2;
      wi[base]             = gi0;
      wi[base + T_DIM]     = gi1;
      wi[base + 2 * T_DIM] = gi2;
    }
  }
}

// K3: merge the NSPLIT partial top-3 lists, causal-pool the indices, gather
// harmonic_loc rows, sum over K, threshold, write (B,C,F,T) coalesced.
__global__ __launch_bounds__(256, 4)
void hi_k3_pool_gather(const float* __restrict__ wv, const int* __restrict__ wi,
                       const float* __restrict__ hl, float* __restrict__ out) {
  const int tid = threadIdx.x;
  const int t0 = blockIdx.x * 64;
  const int bc = blockIdx.y;

  __shared__ float pos_lds[66 * KTOP];   // t0-2 .. t0+63
  __shared__ int   rows[64 * KTOP];
  __shared__ float S[64 * 65];           // [t_local][f_chunk] transpose buffer

  if (tid < 66) {
    int t = t0 - 2 + tid;
    float p0 = PADV, p1 = PADV, p2 = PADV;
    if (t >= 0 && t < T_DIM) {
      float v0 = -INFINITY, v1 = -INFINITY, v2 = -INFINITY;
      int i0 = 0, i1 = 0, i2 = 0;
      for (int sp = 0; sp < NSPLIT; ++sp)        // ascending h ranges
        for (int j = 0; j < KTOP; ++j) {         // descending values
          size_t idx = ((size_t)(bc * NSPLIT + sp) * KTOP + j) * T_DIM + t;
          ins3(wv[idx], wi[idx], v0, v1, v2, i0, i1, i2);
        }
      p0 = (float)i0; p1 = (float)i1; p2 = (float)i2;
    }
    pos_lds[tid * KTOP + 0] = p0;
    pos_lds[tid * KTOP + 1] = p1;
    pos_lds[tid * KTOP + 2] = p2;
  }
  __syncthreads();
  if (tid < 64) {
    // out t = t0+tid; taps are pos[t-2], pos[t-1], pos[t] -> lds j = tid,tid+1,tid+2
#pragma unroll
    for (int k = 0; k < KTOP; ++k) {
      float s = (pos_lds[tid * KTOP + k] + pos_lds[(tid + 1) * KTOP + k])
                + pos_lds[(tid + 2) * KTOP + k];
      rows[tid * KTOP + k] = (int)(s / 3.0f);   // matches ref fp32 /3 + int cast
    }
  }
  __syncthreads();

  const int w = tid >> 6, lane = tid & 63;
  for (int fc = 0; fc < 6; ++fc) {
    const int f0 = fc * 64;
    // gather: each wave covers 16 t values; lanes run over f -> coalesced
    for (int i = 0; i < 16; ++i) {
      int tl = w * 16 + i;
      int r0 = rows[tl * KTOP + 0];
      int r1 = rows[tl * KTOP + 1];
      int r2 = rows[tl * KTOP + 2];
      int f = f0 + lane;
      float s = 0.f;
      if (f < F_DIM)
        s = (hl[(size_t)r0 * F_DIM + f] + hl[(size_t)r1 * F_DIM + f])
            + hl[(size_t)r2 * F_DIM + f];
      S[tl * 65 + lane] = s;
    }
    __syncthreads();
    // write: lanes run over t -> coalesced stores along T
#pragma unroll
    for (int i = 0; i < 16; ++i) {
      int e = tid + 256 * i;
      int fl = e >> 6, tl = e & 63;
      int f = f0 + fl, t = t0 + tl;
      if (f < F_DIM && t < T_DIM)
        out[((size_t)bc * F_DIM + f) * T_DIM + t] = (S[tl * 65 + fl] > 0.f) ? 1.f : 0.f;
    }
    __syncthreads();
  }
}

extern "C" void kernel_launch(void* const* d_in, const int* in_sizes, int n_in,
                              void* d_out, int out_size, void* d_ws, size_t ws_size,
                              hipStream_t stream) {
  const float* mag = (const float*)d_in[0];   // (8,2,321,1000)
  const float* im  = (const float*)d_in[1];   // (4200,321)
  const float* hl  = (const float*)d_in[2];   // (4200,321)
  float* out = (float*)d_out;                 // (8,2,321,1000)

  // ws layout: wv [16][NSPLIT][3][1000] floats, then wi same in ints (~1.5 MB)
  float* wv = (float*)d_ws;
  int*   wi = (int*)d_ws + (size_t)NBC * NSPLIT * KTOP * T_DIM;

  dim3 g1((T_DIM + BN - 1) / BN, NBC, NSPLIT);   // 8 x 16 x 4 = 512 blocks
  hipLaunchKernelGGL(hi_k1_gemm_top3, g1, dim3(256), 0, stream, mag, im, wv, wi);

  dim3 g3((T_DIM + 63) / 64, NBC);               // 16 x 16 = 256 blocks
  hipLaunchKernelGGL(hi_k3_pool_gather, g3, dim3(256), 0, stream, wv, wi, hl, out);
}